// Round 12
// baseline (226.757 us; speedup 1.0000x reference)
//
#include <hip/hip_runtime.h>
#include <hip/hip_bf16.h>

// FraudGNN: 2-layer GraphSAGE (mean aggr) + linear head.
// N=100000, E=1600000, feat 48 -> 32 -> 16 -> 2. fp32 in/out, int edge_index.
//
// R21 = R20 resubmitted (R11 bench died in container acquisition, same infra
// failure mode as R6; audit found no kernel fault path: ws bounds clear,
// kg1 LDS 60.7KB < 64KB, scatter bounds-checked).
// R20 = R19 (best, 173.2us) + single-pass bucket1:
//  R19 profile decomposition: harness ws-repoison fill ~44us (uncontrollable)
//  + k1 44.8 + kg1 ~48 + g2 ~36. k1's bucket branch did TWO ei sweeps +
//  LDS hist/reserve (253K bank conflicts, 3 barriers) just to batch the
//  global reservation. Now: one sweep, per-edge atomicAdd on PADDED global
//  counters bsize_pad[bk*64] (256B apart -> distinct L2 lines, parallel
//  channels; ~4.1K atomics/line ~= 3-7us hidden). Deletes hist/base arrays,
//  one sweep, 2 barriers, all bucket LDS conflicts.
//  k1 lin split (P-only/R-only, VGPR 64) kept from R19. kg1/g2 frozen.

constexpr int NN  = 100000;
constexpr int NE  = 1600000;
constexpr int NLN = 391;                   // lin blocks per half (256 nodes each)
constexpr int NB  = 391;                   // buckets = dst >> 8
constexpr int CAP = 4608;                  // per-bucket capacity (mean 4092, +8 sigma)
constexpr int SEG = CAP + 3 * 256;         // padded bucket CSR footprint
constexpr int T1  = 2048;                  // edges per bucket1 block
constexpr int NB1 = (NE + T1 - 1) / T1;    // 782 bucket1 blocks

__device__ __forceinline__ float bl(unsigned u) { return __uint_as_float(u << 16); }
__device__ __forceinline__ float bh(unsigned u) { return __uint_as_float(u & 0xffff0000u); }
__device__ __forceinline__ unsigned f2b(float x) {
    unsigned u = __float_as_uint(x);
    return (u + 0x7fffu + ((u >> 16) & 1u)) >> 16;
}
__device__ __forceinline__ unsigned pack2(float a, float b) {
    return f2b(a) | (f2b(b) << 16);
}

__device__ __forceinline__ int wave_incl_scan(int v, int lane) {
#pragma unroll
    for (int d = 1; d < 64; d <<= 1) {
        int t = __shfl_up(v, d, 64);
        if (lane >= d) v += t;
    }
    return v;
}

// ---- K1: lin-P [0,391) || lin-R [391,782) || bucket1 [782,1564) ------------
__global__ __launch_bounds__(256) void k1_kernel(
    const float* __restrict__ X,
    const float* __restrict__ Wl,
    const float* __restrict__ Wr,
    const int*   __restrict__ ei,
    int* __restrict__ bsize_pad,               // [NB*64], stride-64 counters
    unsigned* __restrict__ bbuf,
    __hip_bfloat16* __restrict__ P, __hip_bfloat16* __restrict__ R)
{
    __shared__ float sW1[48 * 32];              // 6 KB (lin branches)
    __shared__ int s_any;

    if (blockIdx.x < 2 * NLN) {
        // ---- lin half: out = X @ W, W = Wl (P) or Wr (R). R9 loop verbatim.
        const bool isP = blockIdx.x < NLN;
        const float* W = isP ? Wl : Wr;
        __hip_bfloat16* O = isP ? P : R;
        for (int i = threadIdx.x; i < 48 * 32; i += 256)
            sW1[i] = W[i];
        __syncthreads();
        int n = (blockIdx.x - (isP ? 0 : NLN)) * 256 + threadIdx.x;
        if (n > NN) return;
        if (n == NN) {                           // zero pad row (p1 only used)
            if (isP) {
                uint4 z = make_uint4(0, 0, 0, 0);
                uint4* pp = reinterpret_cast<uint4*>(P + (size_t)NN * 32);
#pragma unroll
                for (int i = 0; i < 4; ++i) pp[i] = z;
            }
            return;
        }
        float xr[48];
        const float4* xp = reinterpret_cast<const float4*>(X + (size_t)n * 48);
#pragma unroll
        for (int i = 0; i < 12; ++i) {
            float4 u = xp[i];
            xr[i*4+0] = u.x; xr[i*4+1] = u.y; xr[i*4+2] = u.z; xr[i*4+3] = u.w;
        }
        float acc[32];
#pragma unroll
        for (int j = 0; j < 32; ++j) acc[j] = 0.f;
#pragma unroll
        for (int k = 0; k < 48; ++k) {
            float xk = xr[k];
#pragma unroll
            for (int j = 0; j < 32; ++j)
                acc[j] += xk * sW1[k * 32 + j];
        }
        uint4* op = reinterpret_cast<uint4*>(O + (size_t)n * 32);
#pragma unroll
        for (int i = 0; i < 4; ++i) {
            uint4 u;
            u.x = pack2(acc[i*8+0], acc[i*8+1]); u.y = pack2(acc[i*8+2], acc[i*8+3]);
            u.z = pack2(acc[i*8+4], acc[i*8+5]); u.w = pack2(acc[i*8+6], acc[i*8+7]);
            op[i] = u;
        }
    } else {
        // ---- bucket1: SINGLE-pass scatter, padded global counters ----------
        if (threadIdx.x == 0) s_any = 0;
        __syncthreads();
        // self-detect edge_index layout: int64 -> odd words all zero
        int dv = 0;
        for (int i = threadIdx.x; i < 2048; i += 256) dv |= ei[2 * i + 1];
        if (dv != 0) atomicOr(&s_any, 1);
        __syncthreads();
        const bool i64 = (s_any == 0);
        const int e0 = (blockIdx.x - 2 * NLN) * T1;

        auto emit = [&](int s, int d) {
            if ((unsigned)s < (unsigned)NN && (unsigned)d < (unsigned)NN) {
                int bk = d >> 8;
                int pos = atomicAdd(&bsize_pad[bk << 6], 1);
                if (pos < CAP)
                    bbuf[(size_t)bk * CAP + pos] =
                        ((unsigned)s << 8) | (unsigned)(d & 255);
            }
        };

        if (i64) {
            const int4* sp = reinterpret_cast<const int4*>(ei) + (e0 >> 1);
            const int4* dp = reinterpret_cast<const int4*>(ei) + ((NE + e0) >> 1);
#pragma unroll
            for (int it = 0; it < 4; ++it) {
                int p = it * 256 + threadIdx.x;  // pair index
                int e = e0 + 2 * p;
                if (e + 2 <= NE) {
                    int4 s4 = sp[p], d4 = dp[p]; // (lo,hi,lo,hi)
                    emit(s4.x, d4.x);
                    emit(s4.z, d4.z);
                } else {
                    for (int e2 = e; e2 < NE && e2 < e + 2; ++e2)
                        emit(ei[(size_t)e2 << 1], ei[(size_t)(NE + e2) << 1]);
                }
            }
        } else {
            const int4* sp = reinterpret_cast<const int4*>(ei) + (e0 >> 2);
            const int4* dp = reinterpret_cast<const int4*>(ei) + ((NE + e0) >> 2);
#pragma unroll
            for (int it = 0; it < 2; ++it) {
                int q = it * 256 + threadIdx.x;  // quad index
                int e = e0 + 4 * q;
                if (e + 4 <= NE) {
                    int4 s4 = sp[q], d4 = dp[q];
                    emit(s4.x, d4.x);
                    emit(s4.y, d4.y);
                    emit(s4.z, d4.z);
                    emit(s4.w, d4.w);
                } else {
                    for (int e2 = e; e2 < NE && e2 < e + 4; ++e2)
                        emit(ei[e2], ei[NE + e2]);
                }
            }
        }
    }
}

// ---- KG1: per bucket (1024 thr) — LDS CSR build + global CSR write +
//           layer1 gather (LDS idx) + update + layer2 projections -----------
__global__ __launch_bounds__(1024) void kg1_kernel(
    const int* __restrict__ bsize_pad, const unsigned* __restrict__ bbuf,
    const __hip_bfloat16* __restrict__ p1,     // [N+1,32] (row NN = 0)
    const __hip_bfloat16* __restrict__ r1,     // [N,32]
    const float* __restrict__ b1,              // [32]
    const float* __restrict__ W2l,             // [32,16]
    const float* __restrict__ W2r,             // [32,16]
    int* __restrict__ csr_g,                   // [NB*SEG] for g2
    int* __restrict__ deg_g,                   // [N]
    int* __restrict__ rows_g,                  // [N]
    __hip_bfloat16* __restrict__ P2,           // [N+1,16] (row NN = 0)
    __hip_bfloat16* __restrict__ R2)           // [N+1,16]
{
    __shared__ alignas(16) int csr[SEG + 8];   // 21.5 KB (+idx prefetch pad)
    __shared__ int ldeg[256], lcur[256], ws[4];
    __shared__ float sW2l[32 * 16], sW2r[32 * 16], sb1[32];
    __shared__ float shh[32 * 257];            // 32.9 KB, odd stride

    int t = threadIdx.x, b = blockIdx.x;
    if (t < 512) { sW2l[t] = W2l[t]; sW2r[t] = W2r[t]; }
    else if (t < 544) sb1[t - 512] = b1[t - 512];
    if (t < 256) ldeg[t] = 0;
    __syncthreads();

    // ---- CSR build (k2's verified 1024-thread phases, LDS destination) ----
    int S = min(bsize_pad[b << 6], CAP);
    const unsigned* bp = bbuf + (size_t)b * CAP;
    for (int i = t; i < S; i += 1024)
        atomicAdd(&ldeg[bp[i] & 255u], 1);
    __syncthreads();

    int v = 0, pv = 0, incl = 0, excl = 0;
    if (t < 256) {
        v  = ldeg[t];
        pv = (v + 3) & ~3;
        incl = wave_incl_scan(pv, t & 63);
        if ((t & 63) == 63) ws[t >> 6] = incl;
    }
    __syncthreads();
    if (t < 256) {
        int off = 0, wid = t >> 6;
#pragma unroll
        for (int w = 0; w < 3; ++w)
            if (wid > w) off += ws[w];
        excl = off + incl - pv;
        lcur[t] = excl;
        int node = (b << 8) + t;
        if (node < NN) {
            deg_g[node] = v;
            rows_g[node] = b * SEG + excl;      // global CSR coords for g2
        }
    }
    __syncthreads();
    for (int i = t; i < S; i += 1024) {
        unsigned pk = bp[i];
        int pos = atomicAdd(&lcur[pk & 255u], 1);
        csr[pos] = (int)(pk >> 8);
    }
    if (t < 256)
        for (int p = excl + v; p < excl + pv; ++p)
            csr[p] = NN;
    __syncthreads();

    // ---- publish CSR once for g2 (overlaps with gather issue below) -------
    for (int p = t; p < SEG; p += 1024)
        csr_g[b * SEG + p] = csr[p];            // trailing garbage never used
                                                // as an index (deg bounds it)

    // ---- layer-1 gather: 4 lanes/node, unroll-2x4, LDS indices ------------
    int loc = t >> 2, c = t & 3;
    int n = (b << 8) + loc;
    if (n < NN) {
        int dn = ldeg[loc];
        int start = lcur[loc] - dn;             // lcur ended at excl+v
        int pv4 = ((dn + 3) & ~3) >> 2;
        const uint4* prow = reinterpret_cast<const uint4*>(p1);
        const int4* cp4 = reinterpret_cast<const int4*>(csr + start);
        uint4 r = reinterpret_cast<const uint4*>(r1)[(size_t)n * 4 + c];
        float acc[8];
#pragma unroll
        for (int j = 0; j < 8; ++j) acc[j] = 0.f;
        int k = 0;
        int4 sA = cp4[0];                       // pad keeps LDS reads in-bounds
        int4 sB = cp4[1];
        for (; k + 1 < pv4; k += 2) {
            int4 nA = cp4[k + 2];
            int4 nB = cp4[k + 3];
            uint4 a = prow[(size_t)sA.x * 4 + c];
            uint4 bq = prow[(size_t)sA.y * 4 + c];
            uint4 d = prow[(size_t)sA.z * 4 + c];
            uint4 e = prow[(size_t)sA.w * 4 + c];
            uint4 f = prow[(size_t)sB.x * 4 + c];
            uint4 g = prow[(size_t)sB.y * 4 + c];
            uint4 hq = prow[(size_t)sB.z * 4 + c];
            uint4 m = prow[(size_t)sB.w * 4 + c];
            acc[0] += bl(a.x) + bl(bq.x) + bl(d.x) + bl(e.x)
                    + bl(f.x) + bl(g.x) + bl(hq.x) + bl(m.x);
            acc[1] += bh(a.x) + bh(bq.x) + bh(d.x) + bh(e.x)
                    + bh(f.x) + bh(g.x) + bh(hq.x) + bh(m.x);
            acc[2] += bl(a.y) + bl(bq.y) + bl(d.y) + bl(e.y)
                    + bl(f.y) + bl(g.y) + bl(hq.y) + bl(m.y);
            acc[3] += bh(a.y) + bh(bq.y) + bh(d.y) + bh(e.y)
                    + bh(f.y) + bh(g.y) + bh(hq.y) + bh(m.y);
            acc[4] += bl(a.z) + bl(bq.z) + bl(d.z) + bl(e.z)
                    + bl(f.z) + bl(g.z) + bl(hq.z) + bl(m.z);
            acc[5] += bh(a.z) + bh(bq.z) + bh(d.z) + bh(e.z)
                    + bh(f.z) + bh(g.z) + bh(hq.z) + bh(m.z);
            acc[6] += bl(a.w) + bl(bq.w) + bl(d.w) + bl(e.w)
                    + bl(f.w) + bl(g.w) + bl(hq.w) + bl(m.w);
            acc[7] += bh(a.w) + bh(bq.w) + bh(d.w) + bh(e.w)
                    + bh(f.w) + bh(g.w) + bh(hq.w) + bh(m.w);
            sA = nA; sB = nB;
        }
        if (k < pv4) {                          // odd tail: one quad
            uint4 a = prow[(size_t)sA.x * 4 + c];
            uint4 bq = prow[(size_t)sA.y * 4 + c];
            uint4 d = prow[(size_t)sA.z * 4 + c];
            uint4 e = prow[(size_t)sA.w * 4 + c];
            acc[0] += bl(a.x) + bl(bq.x) + bl(d.x) + bl(e.x);
            acc[1] += bh(a.x) + bh(bq.x) + bh(d.x) + bh(e.x);
            acc[2] += bl(a.y) + bl(bq.y) + bl(d.y) + bl(e.y);
            acc[3] += bh(a.y) + bh(bq.y) + bh(d.y) + bh(e.y);
            acc[4] += bl(a.z) + bl(bq.z) + bl(d.z) + bl(e.z);
            acc[5] += bh(a.z) + bh(bq.z) + bh(d.z) + bh(e.z);
            acc[6] += bl(a.w) + bl(bq.w) + bl(d.w) + bl(e.w);
            acc[7] += bh(a.w) + bh(bq.w) + bh(d.w) + bh(e.w);
        }
        float inv = 1.0f / fmaxf((float)dn, 1.0f);
        float rr[8] = { bl(r.x), bh(r.x), bl(r.y), bh(r.y),
                        bl(r.z), bh(r.z), bl(r.w), bh(r.w) };
#pragma unroll
        for (int j = 0; j < 8; ++j)
            shh[(c * 8 + j) * 257 + loc] =
                fmaxf(acc[j] * inv + rr[j] + sb1[c * 8 + j], 0.f);
    } else if (n == NN) {                       // zero row for layer-2 pads
        uint2 z = make_uint2(0, 0);
        reinterpret_cast<uint2*>(P2)[(size_t)NN * 4 + c] = z;
        reinterpret_cast<uint2*>(R2)[(size_t)NN * 4 + c] = z;
    }
    __syncthreads();

    // ---- layer-2 projections (kg1-verified indexing) ----------------------
    if (n < NN) {
        float accp[4], accr[4];
#pragma unroll
        for (int j = 0; j < 4; ++j) { accp[j] = 0.f; accr[j] = 0.f; }
#pragma unroll
        for (int k2i = 0; k2i < 32; ++k2i) {
            float hk = shh[k2i * 257 + loc];
#pragma unroll
            for (int j = 0; j < 4; ++j) {
                accp[j] += hk * sW2l[k2i * 16 + c * 4 + j];
                accr[j] += hk * sW2r[k2i * 16 + c * 4 + j];
            }
        }
        uint2 up, ur;
        up.x = pack2(accp[0], accp[1]); up.y = pack2(accp[2], accp[3]);
        ur.x = pack2(accr[0], accr[1]); ur.y = pack2(accr[2], accr[3]);
        reinterpret_cast<uint2*>(P2)[(size_t)n * 4 + c] = up;
        reinterpret_cast<uint2*>(R2)[(size_t)n * 4 + c] = ur;
    }
}

// ---- G2: layer2 gather (R14 verbatim) fused with final head -----------------
__global__ __launch_bounds__(256) void gather2_kernel(
    const int* __restrict__ rowstart, const int* __restrict__ deg,
    const int* __restrict__ csr_src,
    const __hip_bfloat16* __restrict__ P2,
    const __hip_bfloat16* __restrict__ R2,
    const float* __restrict__ b2,       // [16]
    const float* __restrict__ Wlin,     // [16,2]
    const float* __restrict__ blin,     // [2]
    float* __restrict__ out)            // [NN,2]
{
    __shared__ float sb[16], sW[32], sbl[2];
    if (threadIdx.x < 16) sb[threadIdx.x] = b2[threadIdx.x];
    else if (threadIdx.x < 48) sW[threadIdx.x - 16] = Wlin[threadIdx.x - 16];
    else if (threadIdx.x < 50) sbl[threadIdx.x - 48] = blin[threadIdx.x - 48];
    __syncthreads();
    int t = blockIdx.x * 256 + threadIdx.x;
    int n = t >> 1, c = t & 1;
    if (n >= NN) return;
    int start = rowstart[n], dn = deg[n];
    int pv4 = ((dn + 3) & ~3) >> 2;

    const uint4* prow = reinterpret_cast<const uint4*>(P2);
    const int4* cp4 = reinterpret_cast<const int4*>(csr_src + start);
    uint4 r = reinterpret_cast<const uint4*>(R2)[(size_t)n * 2 + c];
    float acc[8];
#pragma unroll
    for (int j = 0; j < 8; ++j) acc[j] = 0.f;
    int k = 0;
    int4 sA = cp4[0];
    int4 sB = cp4[1];
    for (; k + 1 < pv4; k += 2) {
        int4 nA = cp4[k + 2];
        int4 nB = cp4[k + 3];
        uint4 a = prow[(size_t)sA.x * 2 + c];
        uint4 b = prow[(size_t)sA.y * 2 + c];
        uint4 d = prow[(size_t)sA.z * 2 + c];
        uint4 e = prow[(size_t)sA.w * 2 + c];
        uint4 f = prow[(size_t)sB.x * 2 + c];
        uint4 g = prow[(size_t)sB.y * 2 + c];
        uint4 h = prow[(size_t)sB.z * 2 + c];
        uint4 m = prow[(size_t)sB.w * 2 + c];
        acc[0] += bl(a.x) + bl(b.x) + bl(d.x) + bl(e.x)
                + bl(f.x) + bl(g.x) + bl(h.x) + bl(m.x);
        acc[1] += bh(a.x) + bh(b.x) + bh(d.x) + bh(e.x)
                + bh(f.x) + bh(g.x) + bh(h.x) + bh(m.x);
        acc[2] += bl(a.y) + bl(b.y) + bl(d.y) + bl(e.y)
                + bl(f.y) + bl(g.y) + bl(h.y) + bl(m.y);
        acc[3] += bh(a.y) + bh(b.y) + bh(d.y) + bh(e.y)
                + bh(f.y) + bh(g.y) + bh(h.y) + bh(m.y);
        acc[4] += bl(a.z) + bl(b.z) + bl(d.z) + bl(e.z)
                + bl(f.z) + bl(g.z) + bl(h.z) + bl(m.z);
        acc[5] += bh(a.z) + bh(b.z) + bh(d.z) + bh(e.z)
                + bh(f.z) + bh(g.z) + bh(h.z) + bh(m.z);
        acc[6] += bl(a.w) + bl(b.w) + bl(d.w) + bl(e.w)
                + bl(f.w) + bl(g.w) + bl(h.w) + bl(m.w);
        acc[7] += bh(a.w) + bh(b.w) + bh(d.w) + bh(e.w)
                + bh(f.w) + bh(g.w) + bh(h.w) + bh(m.w);
        sA = nA; sB = nB;
    }
    if (k < pv4) {
        uint4 a = prow[(size_t)sA.x * 2 + c];
        uint4 b = prow[(size_t)sA.y * 2 + c];
        uint4 d = prow[(size_t)sA.z * 2 + c];
        uint4 e = prow[(size_t)sA.w * 2 + c];
        acc[0] += bl(a.x) + bl(b.x) + bl(d.x) + bl(e.x);
        acc[1] += bh(a.x) + bh(b.x) + bh(d.x) + bh(e.x);
        acc[2] += bl(a.y) + bl(b.y) + bl(d.y) + bl(e.y);
        acc[3] += bh(a.y) + bh(b.y) + bh(d.y) + bh(e.y);
        acc[4] += bl(a.z) + bl(b.z) + bl(d.z) + bl(e.z);
        acc[5] += bh(a.z) + bh(b.z) + bh(d.z) + bh(e.z);
        acc[6] += bl(a.w) + bl(b.w) + bl(d.w) + bl(e.w);
        acc[7] += bh(a.w) + bh(b.w) + bh(d.w) + bh(e.w);
    }
    float inv = 1.0f / fmaxf((float)dn, 1.0f);
    float rr[8] = { bl(r.x), bh(r.x), bl(r.y), bh(r.y),
                    bl(r.z), bh(r.z), bl(r.w), bh(r.w) };
    float o0 = 0.f, o1 = 0.f;
#pragma unroll
    for (int j = 0; j < 8; ++j) {
        int kk = c * 8 + j;
        float hv = fmaxf(acc[j] * inv + rr[j] + sb[kk], 0.f);
        o0 += hv * sW[kk * 2];
        o1 += hv * sW[kk * 2 + 1];
    }
    o0 += __shfl_xor(o0, 1, 64);
    o1 += __shfl_xor(o1, 1, 64);
    if (c == 0)
        reinterpret_cast<float2*>(out)[n] = make_float2(o0 + sbl[0], o1 + sbl[1]);
}

extern "C" void kernel_launch(void* const* d_in, const int* in_sizes, int n_in,
                              void* d_out, int out_size, void* d_ws, size_t ws_size,
                              hipStream_t stream)
{
    const float* x    = (const float*)d_in[0];
    const int*   ei   = (const int*)d_in[1];
    const float* W1l  = (const float*)d_in[2];
    const float* W1r  = (const float*)d_in[3];
    const float* b1   = (const float*)d_in[4];
    const float* W2l  = (const float*)d_in[5];
    const float* W2r  = (const float*)d_in[6];
    const float* b2   = (const float*)d_in[7];
    const float* Wlin = (const float*)d_in[8];
    const float* blin = (const float*)d_in[9];
    float* out = (float*)d_out;

    // ---- workspace layout (bytes; ws_size = 256 MiB) ----
    char* wsb = (char*)d_ws;
    int*      deg      = (int*)(wsb + 4096);            // int[N]
    int*      rowstart = (int*)(wsb + 404096);          // int[N]
    int*      csr_g    = (int*)(wsb + 804096);          // int[NB*SEG] 8.41 MB
    unsigned* bbuf     = (unsigned*)(wsb + 9300000);    // u32[NB*CAP] 7.21 MB
    __hip_bfloat16* p1 = (__hip_bfloat16*)(wsb + 16600000); // bf16[N+1,32]
    __hip_bfloat16* r1 = (__hip_bfloat16*)(wsb + 23100000); // bf16[N,32]
    __hip_bfloat16* p2 = (__hip_bfloat16*)(wsb + 29600000); // bf16[N+1,16]
    __hip_bfloat16* r2 = (__hip_bfloat16*)(wsb + 32900000); // bf16[N+1,16]
    int*      bsize_pad = (int*)(wsb + 40000000);       // int[NB*64] 100 KB

    hipMemsetAsync(bsize_pad, 0, NB * 64 * sizeof(int), stream);
    k1_kernel<<<2 * NLN + NB1, dim3(256), 0, stream>>>(
        x, W1l, W1r, ei, bsize_pad, bbuf, p1, r1);
    kg1_kernel<<<NB, dim3(1024), 0, stream>>>(
        bsize_pad, bbuf, p1, r1, b1, W2l, W2r, csr_g, deg, rowstart, p2, r2);
    gather2_kernel<<<(NN * 2 + 255) / 256, dim3(256), 0, stream>>>(
        rowstart, deg, csr_g, p2, r2, b2, Wlin, blin, out);
}

// Round 13
// 173.774 us; speedup vs baseline: 1.3049x; 1.3049x over previous
//
#include <hip/hip_runtime.h>
#include <hip/hip_bf16.h>

// FraudGNN: 2-layer GraphSAGE (mean aggr) + linear head.
// N=100000, E=1600000, feat 48 -> 32 -> 16 -> 2. fp32 in/out, int edge_index.
//
// R22 = R19 restored verbatim (verified best, 173.2us).
//  R20/R21 (single-pass bucket1, per-edge global atomicAdd) hit the
//  reversion trigger: k1 44.8 -> ~98us, WRITE_SIZE 26 -> 94.5MB. Mechanism:
//  per-edge reservation interleaves bucket positions across all 782 blocks,
//  so every 4B bbuf write is a partial-line RMW (64B) -> write combining
//  destroyed. The two-phase sweep's batched reservation IS the coalescing
//  mechanism; its LDS hist cost (253K conflicts) is the cheaper side of the
//  trade by ~55us.
// Structure:
//  k1:  lin-P [0,391) || lin-R [391,782) || bucket1 [782,1564)
//       (split lin halves: VGPR 64, R9-verified inner loop, X read twice —
//        bytes free at 11-21% HBM; bucket: R12-verified two-phase sweep)
//  kg1: per bucket (1024 thr): in-LDS CSR (k2-verified phases) + one global
//       publish for g2 + 4-lane unroll-2 gather (LDS idx) + layer-2 proj.
//  g2:  R14-verified 2-lane unroll-2 gather + fused head (global csr, L2-hot)

constexpr int NN  = 100000;
constexpr int NE  = 1600000;
constexpr int NLN = 391;                   // lin blocks per half (256 nodes each)
constexpr int NB  = 391;                   // buckets = dst >> 8
constexpr int CAP = 4608;                  // per-bucket capacity (mean 4092, +8 sigma)
constexpr int SEG = CAP + 3 * 256;         // padded bucket CSR footprint
constexpr int T1  = 2048;                  // edges per bucket1 block
constexpr int NB1 = (NE + T1 - 1) / T1;    // 782 bucket1 blocks

__device__ __forceinline__ float bl(unsigned u) { return __uint_as_float(u << 16); }
__device__ __forceinline__ float bh(unsigned u) { return __uint_as_float(u & 0xffff0000u); }
__device__ __forceinline__ unsigned f2b(float x) {
    unsigned u = __float_as_uint(x);
    return (u + 0x7fffu + ((u >> 16) & 1u)) >> 16;
}
__device__ __forceinline__ unsigned pack2(float a, float b) {
    return f2b(a) | (f2b(b) << 16);
}

__device__ __forceinline__ int wave_incl_scan(int v, int lane) {
#pragma unroll
    for (int d = 1; d < 64; d <<= 1) {
        int t = __shfl_up(v, d, 64);
        if (lane >= d) v += t;
    }
    return v;
}

// ---- K1: lin-P [0,391) || lin-R [391,782) || bucket1 [782,1564) ------------
__global__ __launch_bounds__(256) void k1_kernel(
    const float* __restrict__ X,
    const float* __restrict__ Wl,
    const float* __restrict__ Wr,
    const int*   __restrict__ ei,
    int* __restrict__ bsize, unsigned* __restrict__ bbuf,
    __hip_bfloat16* __restrict__ P, __hip_bfloat16* __restrict__ R)
{
    __shared__ float sW1[48 * 32];              // 6 KB (lin branches)
    __shared__ int hist[NB], base[NB];          // 3.1 KB (bucket branch)
    __shared__ int s_any;

    if (blockIdx.x < 2 * NLN) {
        // ---- lin half: out = X @ W, W = Wl (P) or Wr (R). R9 loop verbatim.
        const bool isP = blockIdx.x < NLN;
        const float* W = isP ? Wl : Wr;
        __hip_bfloat16* O = isP ? P : R;
        for (int i = threadIdx.x; i < 48 * 32; i += 256)
            sW1[i] = W[i];
        __syncthreads();
        int n = (blockIdx.x - (isP ? 0 : NLN)) * 256 + threadIdx.x;
        if (n > NN) return;
        if (n == NN) {                           // zero pad row (p1 only used)
            if (isP) {
                uint4 z = make_uint4(0, 0, 0, 0);
                uint4* pp = reinterpret_cast<uint4*>(P + (size_t)NN * 32);
#pragma unroll
                for (int i = 0; i < 4; ++i) pp[i] = z;
            }
            return;
        }
        float xr[48];
        const float4* xp = reinterpret_cast<const float4*>(X + (size_t)n * 48);
#pragma unroll
        for (int i = 0; i < 12; ++i) {
            float4 u = xp[i];
            xr[i*4+0] = u.x; xr[i*4+1] = u.y; xr[i*4+2] = u.z; xr[i*4+3] = u.w;
        }
        float acc[32];
#pragma unroll
        for (int j = 0; j < 32; ++j) acc[j] = 0.f;
#pragma unroll
        for (int k = 0; k < 48; ++k) {
            float xk = xr[k];
#pragma unroll
            for (int j = 0; j < 32; ++j)
                acc[j] += xk * sW1[k * 32 + j];
        }
        uint4* op = reinterpret_cast<uint4*>(O + (size_t)n * 32);
#pragma unroll
        for (int i = 0; i < 4; ++i) {
            uint4 u;
            u.x = pack2(acc[i*8+0], acc[i*8+1]); u.y = pack2(acc[i*8+2], acc[i*8+3]);
            u.z = pack2(acc[i*8+4], acc[i*8+5]); u.w = pack2(acc[i*8+6], acc[i*8+7]);
            op[i] = u;
        }
    } else {
        // ---------------- bucket1: coarse sort edges by dst>>8 (R12 sweep) --
        if (threadIdx.x == 0) s_any = 0;
        for (int i = threadIdx.x; i < NB; i += 256) hist[i] = 0;
        __syncthreads();
        // self-detect edge_index layout: int64 -> odd words all zero
        int dv = 0;
        for (int i = threadIdx.x; i < 2048; i += 256) dv |= ei[2 * i + 1];
        if (dv != 0) atomicOr(&s_any, 1);
        __syncthreads();
        const bool i64 = (s_any == 0);
        const int e0 = (blockIdx.x - 2 * NLN) * T1;

        // per-edge visitor sweep over this block's T1 edges, int4-vectorized
        auto sweep = [&](auto&& f) {
            if (i64) {
                const int4* sp = reinterpret_cast<const int4*>(ei) + (e0 >> 1);
                const int4* dp = reinterpret_cast<const int4*>(ei) + ((NE + e0) >> 1);
#pragma unroll
                for (int it = 0; it < 4; ++it) {
                    int p = it * 256 + threadIdx.x;  // pair index
                    int e = e0 + 2 * p;
                    if (e + 2 <= NE) {
                        int4 s4 = sp[p], d4 = dp[p]; // (lo,hi,lo,hi)
                        f(s4.x, d4.x);
                        f(s4.z, d4.z);
                    } else {
                        for (int e2 = e; e2 < NE && e2 < e + 2; ++e2)
                            f(ei[(size_t)e2 << 1], ei[(size_t)(NE + e2) << 1]);
                    }
                }
            } else {
                const int4* sp = reinterpret_cast<const int4*>(ei) + (e0 >> 2);
                const int4* dp = reinterpret_cast<const int4*>(ei) + ((NE + e0) >> 2);
#pragma unroll
                for (int it = 0; it < 2; ++it) {
                    int q = it * 256 + threadIdx.x;  // quad index
                    int e = e0 + 4 * q;
                    if (e + 4 <= NE) {
                        int4 s4 = sp[q], d4 = dp[q];
                        f(s4.x, d4.x);
                        f(s4.y, d4.y);
                        f(s4.z, d4.z);
                        f(s4.w, d4.w);
                    } else {
                        for (int e2 = e; e2 < NE && e2 < e + 4; ++e2)
                            f(ei[e2], ei[NE + e2]);
                    }
                }
            }
        };

        // phase 1: LDS histogram
        sweep([&](int s, int d) {
            if ((unsigned)s < (unsigned)NN && (unsigned)d < (unsigned)NN)
                atomicAdd(&hist[d >> 8], 1);
        });
        __syncthreads();
        // phase 2: reserve global ranges; base[] becomes the allocator cursor
        for (int b = threadIdx.x; b < NB; b += 256) {
            int h = hist[b];
            base[b] = h ? atomicAdd(&bsize[b], h) : 0;
        }
        __syncthreads();
        // phase 3: scatter (re-reads ei from hot L2; no reg staging)
        sweep([&](int s, int d) {
            if ((unsigned)s < (unsigned)NN && (unsigned)d < (unsigned)NN) {
                int bk = d >> 8;
                int pos = atomicAdd(&base[bk], 1);
                if (pos < CAP)
                    bbuf[(size_t)bk * CAP + pos] =
                        ((unsigned)s << 8) | (unsigned)(d & 255);
            }
        });
    }
}

// ---- KG1: per bucket (1024 thr) — LDS CSR build + global CSR write +
//           layer1 gather (LDS idx) + update + layer2 projections -----------
__global__ __launch_bounds__(1024) void kg1_kernel(
    const int* __restrict__ bsize, const unsigned* __restrict__ bbuf,
    const __hip_bfloat16* __restrict__ p1,     // [N+1,32] (row NN = 0)
    const __hip_bfloat16* __restrict__ r1,     // [N,32]
    const float* __restrict__ b1,              // [32]
    const float* __restrict__ W2l,             // [32,16]
    const float* __restrict__ W2r,             // [32,16]
    int* __restrict__ csr_g,                   // [NB*SEG] for g2
    int* __restrict__ deg_g,                   // [N]
    int* __restrict__ rows_g,                  // [N]
    __hip_bfloat16* __restrict__ P2,           // [N+1,16] (row NN = 0)
    __hip_bfloat16* __restrict__ R2)           // [N+1,16]
{
    __shared__ alignas(16) int csr[SEG + 8];   // 21.5 KB (+idx prefetch pad)
    __shared__ int ldeg[256], lcur[256], ws[4];
    __shared__ float sW2l[32 * 16], sW2r[32 * 16], sb1[32];
    __shared__ float shh[32 * 257];            // 32.9 KB, odd stride

    int t = threadIdx.x, b = blockIdx.x;
    if (t < 512) { sW2l[t] = W2l[t]; sW2r[t] = W2r[t]; }
    else if (t < 544) sb1[t - 512] = b1[t - 512];
    if (t < 256) ldeg[t] = 0;
    __syncthreads();

    // ---- CSR build (k2's verified 1024-thread phases, LDS destination) ----
    int S = min(bsize[b], CAP);
    const unsigned* bp = bbuf + (size_t)b * CAP;
    for (int i = t; i < S; i += 1024)
        atomicAdd(&ldeg[bp[i] & 255u], 1);
    __syncthreads();

    int v = 0, pv = 0, incl = 0, excl = 0;
    if (t < 256) {
        v  = ldeg[t];
        pv = (v + 3) & ~3;
        incl = wave_incl_scan(pv, t & 63);
        if ((t & 63) == 63) ws[t >> 6] = incl;
    }
    __syncthreads();
    if (t < 256) {
        int off = 0, wid = t >> 6;
#pragma unroll
        for (int w = 0; w < 3; ++w)
            if (wid > w) off += ws[w];
        excl = off + incl - pv;
        lcur[t] = excl;
        int node = (b << 8) + t;
        if (node < NN) {
            deg_g[node] = v;
            rows_g[node] = b * SEG + excl;      // global CSR coords for g2
        }
    }
    __syncthreads();
    for (int i = t; i < S; i += 1024) {
        unsigned pk = bp[i];
        int pos = atomicAdd(&lcur[pk & 255u], 1);
        csr[pos] = (int)(pk >> 8);
    }
    if (t < 256)
        for (int p = excl + v; p < excl + pv; ++p)
            csr[p] = NN;
    __syncthreads();

    // ---- publish CSR once for g2 (overlaps with gather issue below) -------
    for (int p = t; p < SEG; p += 1024)
        csr_g[b * SEG + p] = csr[p];            // trailing garbage never used
                                                // as an index (deg bounds it)

    // ---- layer-1 gather: 4 lanes/node, unroll-2x4, LDS indices ------------
    int loc = t >> 2, c = t & 3;
    int n = (b << 8) + loc;
    if (n < NN) {
        int dn = ldeg[loc];
        int start = lcur[loc] - dn;             // lcur ended at excl+v
        int pv4 = ((dn + 3) & ~3) >> 2;
        const uint4* prow = reinterpret_cast<const uint4*>(p1);
        const int4* cp4 = reinterpret_cast<const int4*>(csr + start);
        uint4 r = reinterpret_cast<const uint4*>(r1)[(size_t)n * 4 + c];
        float acc[8];
#pragma unroll
        for (int j = 0; j < 8; ++j) acc[j] = 0.f;
        int k = 0;
        int4 sA = cp4[0];                       // pad keeps LDS reads in-bounds
        int4 sB = cp4[1];
        for (; k + 1 < pv4; k += 2) {
            int4 nA = cp4[k + 2];
            int4 nB = cp4[k + 3];
            uint4 a = prow[(size_t)sA.x * 4 + c];
            uint4 bq = prow[(size_t)sA.y * 4 + c];
            uint4 d = prow[(size_t)sA.z * 4 + c];
            uint4 e = prow[(size_t)sA.w * 4 + c];
            uint4 f = prow[(size_t)sB.x * 4 + c];
            uint4 g = prow[(size_t)sB.y * 4 + c];
            uint4 hq = prow[(size_t)sB.z * 4 + c];
            uint4 m = prow[(size_t)sB.w * 4 + c];
            acc[0] += bl(a.x) + bl(bq.x) + bl(d.x) + bl(e.x)
                    + bl(f.x) + bl(g.x) + bl(hq.x) + bl(m.x);
            acc[1] += bh(a.x) + bh(bq.x) + bh(d.x) + bh(e.x)
                    + bh(f.x) + bh(g.x) + bh(hq.x) + bh(m.x);
            acc[2] += bl(a.y) + bl(bq.y) + bl(d.y) + bl(e.y)
                    + bl(f.y) + bl(g.y) + bl(hq.y) + bl(m.y);
            acc[3] += bh(a.y) + bh(bq.y) + bh(d.y) + bh(e.y)
                    + bh(f.y) + bh(g.y) + bh(hq.y) + bh(m.y);
            acc[4] += bl(a.z) + bl(bq.z) + bl(d.z) + bl(e.z)
                    + bl(f.z) + bl(g.z) + bl(hq.z) + bl(m.z);
            acc[5] += bh(a.z) + bh(bq.z) + bh(d.z) + bh(e.z)
                    + bh(f.z) + bh(g.z) + bh(hq.z) + bh(m.z);
            acc[6] += bl(a.w) + bl(bq.w) + bl(d.w) + bl(e.w)
                    + bl(f.w) + bl(g.w) + bl(hq.w) + bl(m.w);
            acc[7] += bh(a.w) + bh(bq.w) + bh(d.w) + bh(e.w)
                    + bh(f.w) + bh(g.w) + bh(hq.w) + bh(m.w);
            sA = nA; sB = nB;
        }
        if (k < pv4) {                          // odd tail: one quad
            uint4 a = prow[(size_t)sA.x * 4 + c];
            uint4 bq = prow[(size_t)sA.y * 4 + c];
            uint4 d = prow[(size_t)sA.z * 4 + c];
            uint4 e = prow[(size_t)sA.w * 4 + c];
            acc[0] += bl(a.x) + bl(bq.x) + bl(d.x) + bl(e.x);
            acc[1] += bh(a.x) + bh(bq.x) + bh(d.x) + bh(e.x);
            acc[2] += bl(a.y) + bl(bq.y) + bl(d.y) + bl(e.y);
            acc[3] += bh(a.y) + bh(bq.y) + bh(d.y) + bh(e.y);
            acc[4] += bl(a.z) + bl(bq.z) + bl(d.z) + bl(e.z);
            acc[5] += bh(a.z) + bh(bq.z) + bh(d.z) + bh(e.z);
            acc[6] += bl(a.w) + bl(bq.w) + bl(d.w) + bl(e.w);
            acc[7] += bh(a.w) + bh(bq.w) + bh(d.w) + bh(e.w);
        }
        float inv = 1.0f / fmaxf((float)dn, 1.0f);
        float rr[8] = { bl(r.x), bh(r.x), bl(r.y), bh(r.y),
                        bl(r.z), bh(r.z), bl(r.w), bh(r.w) };
#pragma unroll
        for (int j = 0; j < 8; ++j)
            shh[(c * 8 + j) * 257 + loc] =
                fmaxf(acc[j] * inv + rr[j] + sb1[c * 8 + j], 0.f);
    } else if (n == NN) {                       // zero row for layer-2 pads
        uint2 z = make_uint2(0, 0);
        reinterpret_cast<uint2*>(P2)[(size_t)NN * 4 + c] = z;
        reinterpret_cast<uint2*>(R2)[(size_t)NN * 4 + c] = z;
    }
    __syncthreads();

    // ---- layer-2 projections (kg1-verified indexing) ----------------------
    if (n < NN) {
        float accp[4], accr[4];
#pragma unroll
        for (int j = 0; j < 4; ++j) { accp[j] = 0.f; accr[j] = 0.f; }
#pragma unroll
        for (int k2i = 0; k2i < 32; ++k2i) {
            float hk = shh[k2i * 257 + loc];
#pragma unroll
            for (int j = 0; j < 4; ++j) {
                accp[j] += hk * sW2l[k2i * 16 + c * 4 + j];
                accr[j] += hk * sW2r[k2i * 16 + c * 4 + j];
            }
        }
        uint2 up, ur;
        up.x = pack2(accp[0], accp[1]); up.y = pack2(accp[2], accp[3]);
        ur.x = pack2(accr[0], accr[1]); ur.y = pack2(accr[2], accr[3]);
        reinterpret_cast<uint2*>(P2)[(size_t)n * 4 + c] = up;
        reinterpret_cast<uint2*>(R2)[(size_t)n * 4 + c] = ur;
    }
}

// ---- G2: layer2 gather (R14 verbatim) fused with final head -----------------
__global__ __launch_bounds__(256) void gather2_kernel(
    const int* __restrict__ rowstart, const int* __restrict__ deg,
    const int* __restrict__ csr_src,
    const __hip_bfloat16* __restrict__ P2,
    const __hip_bfloat16* __restrict__ R2,
    const float* __restrict__ b2,       // [16]
    const float* __restrict__ Wlin,     // [16,2]
    const float* __restrict__ blin,     // [2]
    float* __restrict__ out)            // [NN,2]
{
    __shared__ float sb[16], sW[32], sbl[2];
    if (threadIdx.x < 16) sb[threadIdx.x] = b2[threadIdx.x];
    else if (threadIdx.x < 48) sW[threadIdx.x - 16] = Wlin[threadIdx.x - 16];
    else if (threadIdx.x < 50) sbl[threadIdx.x - 48] = blin[threadIdx.x - 48];
    __syncthreads();
    int t = blockIdx.x * 256 + threadIdx.x;
    int n = t >> 1, c = t & 1;
    if (n >= NN) return;
    int start = rowstart[n], dn = deg[n];
    int pv4 = ((dn + 3) & ~3) >> 2;

    const uint4* prow = reinterpret_cast<const uint4*>(P2);
    const int4* cp4 = reinterpret_cast<const int4*>(csr_src + start);
    uint4 r = reinterpret_cast<const uint4*>(R2)[(size_t)n * 2 + c];
    float acc[8];
#pragma unroll
    for (int j = 0; j < 8; ++j) acc[j] = 0.f;
    int k = 0;
    int4 sA = cp4[0];
    int4 sB = cp4[1];
    for (; k + 1 < pv4; k += 2) {
        int4 nA = cp4[k + 2];
        int4 nB = cp4[k + 3];
        uint4 a = prow[(size_t)sA.x * 2 + c];
        uint4 b = prow[(size_t)sA.y * 2 + c];
        uint4 d = prow[(size_t)sA.z * 2 + c];
        uint4 e = prow[(size_t)sA.w * 2 + c];
        uint4 f = prow[(size_t)sB.x * 2 + c];
        uint4 g = prow[(size_t)sB.y * 2 + c];
        uint4 h = prow[(size_t)sB.z * 2 + c];
        uint4 m = prow[(size_t)sB.w * 2 + c];
        acc[0] += bl(a.x) + bl(b.x) + bl(d.x) + bl(e.x)
                + bl(f.x) + bl(g.x) + bl(h.x) + bl(m.x);
        acc[1] += bh(a.x) + bh(b.x) + bh(d.x) + bh(e.x)
                + bh(f.x) + bh(g.x) + bh(h.x) + bh(m.x);
        acc[2] += bl(a.y) + bl(b.y) + bl(d.y) + bl(e.y)
                + bl(f.y) + bl(g.y) + bl(h.y) + bl(m.y);
        acc[3] += bh(a.y) + bh(b.y) + bh(d.y) + bh(e.y)
                + bh(f.y) + bh(g.y) + bh(h.y) + bh(m.y);
        acc[4] += bl(a.z) + bl(b.z) + bl(d.z) + bl(e.z)
                + bl(f.z) + bl(g.z) + bl(h.z) + bl(m.z);
        acc[5] += bh(a.z) + bh(b.z) + bh(d.z) + bh(e.z)
                + bh(f.z) + bh(g.z) + bh(h.z) + bh(m.z);
        acc[6] += bl(a.w) + bl(b.w) + bl(d.w) + bl(e.w)
                + bl(f.w) + bl(g.w) + bl(h.w) + bl(m.w);
        acc[7] += bh(a.w) + bh(b.w) + bh(d.w) + bh(e.w)
                + bh(f.w) + bh(g.w) + bh(h.w) + bh(m.w);
        sA = nA; sB = nB;
    }
    if (k < pv4) {
        uint4 a = prow[(size_t)sA.x * 2 + c];
        uint4 b = prow[(size_t)sA.y * 2 + c];
        uint4 d = prow[(size_t)sA.z * 2 + c];
        uint4 e = prow[(size_t)sA.w * 2 + c];
        acc[0] += bl(a.x) + bl(b.x) + bl(d.x) + bl(e.x);
        acc[1] += bh(a.x) + bh(b.x) + bh(d.x) + bh(e.x);
        acc[2] += bl(a.y) + bl(b.y) + bl(d.y) + bl(e.y);
        acc[3] += bh(a.y) + bh(b.y) + bh(d.y) + bh(e.y);
        acc[4] += bl(a.z) + bl(b.z) + bl(d.z) + bl(e.z);
        acc[5] += bh(a.z) + bh(b.z) + bh(d.z) + bh(e.z);
        acc[6] += bl(a.w) + bl(b.w) + bl(d.w) + bl(e.w);
        acc[7] += bh(a.w) + bh(b.w) + bh(d.w) + bh(e.w);
    }
    float inv = 1.0f / fmaxf((float)dn, 1.0f);
    float rr[8] = { bl(r.x), bh(r.x), bl(r.y), bh(r.y),
                    bl(r.z), bh(r.z), bl(r.w), bh(r.w) };
    float o0 = 0.f, o1 = 0.f;
#pragma unroll
    for (int j = 0; j < 8; ++j) {
        int kk = c * 8 + j;
        float hv = fmaxf(acc[j] * inv + rr[j] + sb[kk], 0.f);
        o0 += hv * sW[kk * 2];
        o1 += hv * sW[kk * 2 + 1];
    }
    o0 += __shfl_xor(o0, 1, 64);
    o1 += __shfl_xor(o1, 1, 64);
    if (c == 0)
        reinterpret_cast<float2*>(out)[n] = make_float2(o0 + sbl[0], o1 + sbl[1]);
}

extern "C" void kernel_launch(void* const* d_in, const int* in_sizes, int n_in,
                              void* d_out, int out_size, void* d_ws, size_t ws_size,
                              hipStream_t stream)
{
    const float* x    = (const float*)d_in[0];
    const int*   ei   = (const int*)d_in[1];
    const float* W1l  = (const float*)d_in[2];
    const float* W1r  = (const float*)d_in[3];
    const float* b1   = (const float*)d_in[4];
    const float* W2l  = (const float*)d_in[5];
    const float* W2r  = (const float*)d_in[6];
    const float* b2   = (const float*)d_in[7];
    const float* Wlin = (const float*)d_in[8];
    const float* blin = (const float*)d_in[9];
    float* out = (float*)d_out;

    // ---- workspace layout (bytes; ws_size = 256 MiB) ----
    char* wsb = (char*)d_ws;
    int*      bsize    = (int*)(wsb + 64);              // int[NB]
    int*      deg      = (int*)(wsb + 4096);            // int[N]
    int*      rowstart = (int*)(wsb + 404096);          // int[N]
    int*      csr_g    = (int*)(wsb + 804096);          // int[NB*SEG] 8.41 MB
    unsigned* bbuf     = (unsigned*)(wsb + 9300000);    // u32[NB*CAP] 7.21 MB
    __hip_bfloat16* p1 = (__hip_bfloat16*)(wsb + 16600000); // bf16[N+1,32]
    __hip_bfloat16* r1 = (__hip_bfloat16*)(wsb + 23100000); // bf16[N,32]
    __hip_bfloat16* p2 = (__hip_bfloat16*)(wsb + 29600000); // bf16[N+1,16]
    __hip_bfloat16* r2 = (__hip_bfloat16*)(wsb + 32900000); // bf16[N+1,16]

    hipMemsetAsync(bsize, 0, NB * sizeof(int), stream);
    k1_kernel<<<2 * NLN + NB1, dim3(256), 0, stream>>>(
        x, W1l, W1r, ei, bsize, bbuf, p1, r1);
    kg1_kernel<<<NB, dim3(1024), 0, stream>>>(
        bsize, bbuf, p1, r1, b1, W2l, W2r, csr_g, deg, rowstart, p2, r2);
    gather2_kernel<<<(NN * 2 + 255) / 256, dim3(256), 0, stream>>>(
        rowstart, deg, csr_g, p2, r2, b2, Wlin, blin, out);
}

// Round 14
// 171.799 us; speedup vs baseline: 1.3199x; 1.0115x over previous
//
#include <hip/hip_runtime.h>
#include <hip/hip_bf16.h>

// FraudGNN: 2-layer GraphSAGE (mean aggr) + linear head.
// N=100000, E=1600000, feat 48 -> 32 -> 16 -> 2. fp32 in/out, int edge_index.
//
// R23 = R22 (re-anchored best, 173.8us) + g2 at 4 lanes/node.
//  R22 decomposition: fill ~44 (harness re-poison, uncontrollable) + k1 43.9
//  + kg1 ~48 + g2 ~36. g2 was grid-limited: 200K threads = 12.2 waves/CU.
//  Now 4 lanes/node (uint2 per lane, acc[4], quad shfl-reduce head — the
//  R18-eg2-verified pattern) -> 400K threads = 24.4 waves/CU, same bytes.
// Frozen: k1 (split lin P/R + two-phase bucket sweep; R20's single-pass
//  atomic scatter refuted: WRITE 26->94MB partial-line RMW), kg1 (in-LDS CSR
//  + publish + 4-lane gather + proj; fully resident at 391 blocks).

constexpr int NN  = 100000;
constexpr int NE  = 1600000;
constexpr int NLN = 391;                   // lin blocks per half (256 nodes each)
constexpr int NB  = 391;                   // buckets = dst >> 8
constexpr int CAP = 4608;                  // per-bucket capacity (mean 4092, +8 sigma)
constexpr int SEG = CAP + 3 * 256;         // padded bucket CSR footprint
constexpr int T1  = 2048;                  // edges per bucket1 block
constexpr int NB1 = (NE + T1 - 1) / T1;    // 782 bucket1 blocks

__device__ __forceinline__ float bl(unsigned u) { return __uint_as_float(u << 16); }
__device__ __forceinline__ float bh(unsigned u) { return __uint_as_float(u & 0xffff0000u); }
__device__ __forceinline__ unsigned f2b(float x) {
    unsigned u = __float_as_uint(x);
    return (u + 0x7fffu + ((u >> 16) & 1u)) >> 16;
}
__device__ __forceinline__ unsigned pack2(float a, float b) {
    return f2b(a) | (f2b(b) << 16);
}

__device__ __forceinline__ int wave_incl_scan(int v, int lane) {
#pragma unroll
    for (int d = 1; d < 64; d <<= 1) {
        int t = __shfl_up(v, d, 64);
        if (lane >= d) v += t;
    }
    return v;
}

// ---- K1: lin-P [0,391) || lin-R [391,782) || bucket1 [782,1564) ------------
__global__ __launch_bounds__(256) void k1_kernel(
    const float* __restrict__ X,
    const float* __restrict__ Wl,
    const float* __restrict__ Wr,
    const int*   __restrict__ ei,
    int* __restrict__ bsize, unsigned* __restrict__ bbuf,
    __hip_bfloat16* __restrict__ P, __hip_bfloat16* __restrict__ R)
{
    __shared__ float sW1[48 * 32];              // 6 KB (lin branches)
    __shared__ int hist[NB], base[NB];          // 3.1 KB (bucket branch)
    __shared__ int s_any;

    if (blockIdx.x < 2 * NLN) {
        // ---- lin half: out = X @ W, W = Wl (P) or Wr (R). R9 loop verbatim.
        const bool isP = blockIdx.x < NLN;
        const float* W = isP ? Wl : Wr;
        __hip_bfloat16* O = isP ? P : R;
        for (int i = threadIdx.x; i < 48 * 32; i += 256)
            sW1[i] = W[i];
        __syncthreads();
        int n = (blockIdx.x - (isP ? 0 : NLN)) * 256 + threadIdx.x;
        if (n > NN) return;
        if (n == NN) {                           // zero pad row (p1 only used)
            if (isP) {
                uint4 z = make_uint4(0, 0, 0, 0);
                uint4* pp = reinterpret_cast<uint4*>(P + (size_t)NN * 32);
#pragma unroll
                for (int i = 0; i < 4; ++i) pp[i] = z;
            }
            return;
        }
        float xr[48];
        const float4* xp = reinterpret_cast<const float4*>(X + (size_t)n * 48);
#pragma unroll
        for (int i = 0; i < 12; ++i) {
            float4 u = xp[i];
            xr[i*4+0] = u.x; xr[i*4+1] = u.y; xr[i*4+2] = u.z; xr[i*4+3] = u.w;
        }
        float acc[32];
#pragma unroll
        for (int j = 0; j < 32; ++j) acc[j] = 0.f;
#pragma unroll
        for (int k = 0; k < 48; ++k) {
            float xk = xr[k];
#pragma unroll
            for (int j = 0; j < 32; ++j)
                acc[j] += xk * sW1[k * 32 + j];
        }
        uint4* op = reinterpret_cast<uint4*>(O + (size_t)n * 32);
#pragma unroll
        for (int i = 0; i < 4; ++i) {
            uint4 u;
            u.x = pack2(acc[i*8+0], acc[i*8+1]); u.y = pack2(acc[i*8+2], acc[i*8+3]);
            u.z = pack2(acc[i*8+4], acc[i*8+5]); u.w = pack2(acc[i*8+6], acc[i*8+7]);
            op[i] = u;
        }
    } else {
        // ---------------- bucket1: coarse sort edges by dst>>8 (R12 sweep) --
        if (threadIdx.x == 0) s_any = 0;
        for (int i = threadIdx.x; i < NB; i += 256) hist[i] = 0;
        __syncthreads();
        // self-detect edge_index layout: int64 -> odd words all zero
        int dv = 0;
        for (int i = threadIdx.x; i < 2048; i += 256) dv |= ei[2 * i + 1];
        if (dv != 0) atomicOr(&s_any, 1);
        __syncthreads();
        const bool i64 = (s_any == 0);
        const int e0 = (blockIdx.x - 2 * NLN) * T1;

        // per-edge visitor sweep over this block's T1 edges, int4-vectorized
        auto sweep = [&](auto&& f) {
            if (i64) {
                const int4* sp = reinterpret_cast<const int4*>(ei) + (e0 >> 1);
                const int4* dp = reinterpret_cast<const int4*>(ei) + ((NE + e0) >> 1);
#pragma unroll
                for (int it = 0; it < 4; ++it) {
                    int p = it * 256 + threadIdx.x;  // pair index
                    int e = e0 + 2 * p;
                    if (e + 2 <= NE) {
                        int4 s4 = sp[p], d4 = dp[p]; // (lo,hi,lo,hi)
                        f(s4.x, d4.x);
                        f(s4.z, d4.z);
                    } else {
                        for (int e2 = e; e2 < NE && e2 < e + 2; ++e2)
                            f(ei[(size_t)e2 << 1], ei[(size_t)(NE + e2) << 1]);
                    }
                }
            } else {
                const int4* sp = reinterpret_cast<const int4*>(ei) + (e0 >> 2);
                const int4* dp = reinterpret_cast<const int4*>(ei) + ((NE + e0) >> 2);
#pragma unroll
                for (int it = 0; it < 2; ++it) {
                    int q = it * 256 + threadIdx.x;  // quad index
                    int e = e0 + 4 * q;
                    if (e + 4 <= NE) {
                        int4 s4 = sp[q], d4 = dp[q];
                        f(s4.x, d4.x);
                        f(s4.y, d4.y);
                        f(s4.z, d4.z);
                        f(s4.w, d4.w);
                    } else {
                        for (int e2 = e; e2 < NE && e2 < e + 4; ++e2)
                            f(ei[e2], ei[NE + e2]);
                    }
                }
            }
        };

        // phase 1: LDS histogram
        sweep([&](int s, int d) {
            if ((unsigned)s < (unsigned)NN && (unsigned)d < (unsigned)NN)
                atomicAdd(&hist[d >> 8], 1);
        });
        __syncthreads();
        // phase 2: reserve global ranges; base[] becomes the allocator cursor
        for (int b = threadIdx.x; b < NB; b += 256) {
            int h = hist[b];
            base[b] = h ? atomicAdd(&bsize[b], h) : 0;
        }
        __syncthreads();
        // phase 3: scatter (re-reads ei from hot L2; no reg staging)
        sweep([&](int s, int d) {
            if ((unsigned)s < (unsigned)NN && (unsigned)d < (unsigned)NN) {
                int bk = d >> 8;
                int pos = atomicAdd(&base[bk], 1);
                if (pos < CAP)
                    bbuf[(size_t)bk * CAP + pos] =
                        ((unsigned)s << 8) | (unsigned)(d & 255);
            }
        });
    }
}

// ---- KG1: per bucket (1024 thr) — LDS CSR build + global CSR write +
//           layer1 gather (LDS idx) + update + layer2 projections -----------
__global__ __launch_bounds__(1024) void kg1_kernel(
    const int* __restrict__ bsize, const unsigned* __restrict__ bbuf,
    const __hip_bfloat16* __restrict__ p1,     // [N+1,32] (row NN = 0)
    const __hip_bfloat16* __restrict__ r1,     // [N,32]
    const float* __restrict__ b1,              // [32]
    const float* __restrict__ W2l,             // [32,16]
    const float* __restrict__ W2r,             // [32,16]
    int* __restrict__ csr_g,                   // [NB*SEG] for g2
    int* __restrict__ deg_g,                   // [N]
    int* __restrict__ rows_g,                  // [N]
    __hip_bfloat16* __restrict__ P2,           // [N+1,16] (row NN = 0)
    __hip_bfloat16* __restrict__ R2)           // [N+1,16]
{
    __shared__ alignas(16) int csr[SEG + 8];   // 21.5 KB (+idx prefetch pad)
    __shared__ int ldeg[256], lcur[256], ws[4];
    __shared__ float sW2l[32 * 16], sW2r[32 * 16], sb1[32];
    __shared__ float shh[32 * 257];            // 32.9 KB, odd stride

    int t = threadIdx.x, b = blockIdx.x;
    if (t < 512) { sW2l[t] = W2l[t]; sW2r[t] = W2r[t]; }
    else if (t < 544) sb1[t - 512] = b1[t - 512];
    if (t < 256) ldeg[t] = 0;
    __syncthreads();

    // ---- CSR build (k2's verified 1024-thread phases, LDS destination) ----
    int S = min(bsize[b], CAP);
    const unsigned* bp = bbuf + (size_t)b * CAP;
    for (int i = t; i < S; i += 1024)
        atomicAdd(&ldeg[bp[i] & 255u], 1);
    __syncthreads();

    int v = 0, pv = 0, incl = 0, excl = 0;
    if (t < 256) {
        v  = ldeg[t];
        pv = (v + 3) & ~3;
        incl = wave_incl_scan(pv, t & 63);
        if ((t & 63) == 63) ws[t >> 6] = incl;
    }
    __syncthreads();
    if (t < 256) {
        int off = 0, wid = t >> 6;
#pragma unroll
        for (int w = 0; w < 3; ++w)
            if (wid > w) off += ws[w];
        excl = off + incl - pv;
        lcur[t] = excl;
        int node = (b << 8) + t;
        if (node < NN) {
            deg_g[node] = v;
            rows_g[node] = b * SEG + excl;      // global CSR coords for g2
        }
    }
    __syncthreads();
    for (int i = t; i < S; i += 1024) {
        unsigned pk = bp[i];
        int pos = atomicAdd(&lcur[pk & 255u], 1);
        csr[pos] = (int)(pk >> 8);
    }
    if (t < 256)
        for (int p = excl + v; p < excl + pv; ++p)
            csr[p] = NN;
    __syncthreads();

    // ---- publish CSR once for g2 (overlaps with gather issue below) -------
    for (int p = t; p < SEG; p += 1024)
        csr_g[b * SEG + p] = csr[p];            // trailing garbage never used
                                                // as an index (deg bounds it)

    // ---- layer-1 gather: 4 lanes/node, unroll-2x4, LDS indices ------------
    int loc = t >> 2, c = t & 3;
    int n = (b << 8) + loc;
    if (n < NN) {
        int dn = ldeg[loc];
        int start = lcur[loc] - dn;             // lcur ended at excl+v
        int pv4 = ((dn + 3) & ~3) >> 2;
        const uint4* prow = reinterpret_cast<const uint4*>(p1);
        const int4* cp4 = reinterpret_cast<const int4*>(csr + start);
        uint4 r = reinterpret_cast<const uint4*>(r1)[(size_t)n * 4 + c];
        float acc[8];
#pragma unroll
        for (int j = 0; j < 8; ++j) acc[j] = 0.f;
        int k = 0;
        int4 sA = cp4[0];                       // pad keeps LDS reads in-bounds
        int4 sB = cp4[1];
        for (; k + 1 < pv4; k += 2) {
            int4 nA = cp4[k + 2];
            int4 nB = cp4[k + 3];
            uint4 a = prow[(size_t)sA.x * 4 + c];
            uint4 bq = prow[(size_t)sA.y * 4 + c];
            uint4 d = prow[(size_t)sA.z * 4 + c];
            uint4 e = prow[(size_t)sA.w * 4 + c];
            uint4 f = prow[(size_t)sB.x * 4 + c];
            uint4 g = prow[(size_t)sB.y * 4 + c];
            uint4 hq = prow[(size_t)sB.z * 4 + c];
            uint4 m = prow[(size_t)sB.w * 4 + c];
            acc[0] += bl(a.x) + bl(bq.x) + bl(d.x) + bl(e.x)
                    + bl(f.x) + bl(g.x) + bl(hq.x) + bl(m.x);
            acc[1] += bh(a.x) + bh(bq.x) + bh(d.x) + bh(e.x)
                    + bh(f.x) + bh(g.x) + bh(hq.x) + bh(m.x);
            acc[2] += bl(a.y) + bl(bq.y) + bl(d.y) + bl(e.y)
                    + bl(f.y) + bl(g.y) + bl(hq.y) + bl(m.y);
            acc[3] += bh(a.y) + bh(bq.y) + bh(d.y) + bh(e.y)
                    + bh(f.y) + bh(g.y) + bh(hq.y) + bh(m.y);
            acc[4] += bl(a.z) + bl(bq.z) + bl(d.z) + bl(e.z)
                    + bl(f.z) + bl(g.z) + bl(hq.z) + bl(m.z);
            acc[5] += bh(a.z) + bh(bq.z) + bh(d.z) + bh(e.z)
                    + bh(f.z) + bh(g.z) + bh(hq.z) + bh(m.z);
            acc[6] += bl(a.w) + bl(bq.w) + bl(d.w) + bl(e.w)
                    + bl(f.w) + bl(g.w) + bl(hq.w) + bl(m.w);
            acc[7] += bh(a.w) + bh(bq.w) + bh(d.w) + bh(e.w)
                    + bh(f.w) + bh(g.w) + bh(hq.w) + bh(m.w);
            sA = nA; sB = nB;
        }
        if (k < pv4) {                          // odd tail: one quad
            uint4 a = prow[(size_t)sA.x * 4 + c];
            uint4 bq = prow[(size_t)sA.y * 4 + c];
            uint4 d = prow[(size_t)sA.z * 4 + c];
            uint4 e = prow[(size_t)sA.w * 4 + c];
            acc[0] += bl(a.x) + bl(bq.x) + bl(d.x) + bl(e.x);
            acc[1] += bh(a.x) + bh(bq.x) + bh(d.x) + bh(e.x);
            acc[2] += bl(a.y) + bl(bq.y) + bl(d.y) + bl(e.y);
            acc[3] += bh(a.y) + bh(bq.y) + bh(d.y) + bh(e.y);
            acc[4] += bl(a.z) + bl(bq.z) + bl(d.z) + bl(e.z);
            acc[5] += bh(a.z) + bh(bq.z) + bh(d.z) + bh(e.z);
            acc[6] += bl(a.w) + bl(bq.w) + bl(d.w) + bl(e.w);
            acc[7] += bh(a.w) + bh(bq.w) + bh(d.w) + bh(e.w);
        }
        float inv = 1.0f / fmaxf((float)dn, 1.0f);
        float rr[8] = { bl(r.x), bh(r.x), bl(r.y), bh(r.y),
                        bl(r.z), bh(r.z), bl(r.w), bh(r.w) };
#pragma unroll
        for (int j = 0; j < 8; ++j)
            shh[(c * 8 + j) * 257 + loc] =
                fmaxf(acc[j] * inv + rr[j] + sb1[c * 8 + j], 0.f);
    } else if (n == NN) {                       // zero row for layer-2 pads
        uint2 z = make_uint2(0, 0);
        reinterpret_cast<uint2*>(P2)[(size_t)NN * 4 + c] = z;
        reinterpret_cast<uint2*>(R2)[(size_t)NN * 4 + c] = z;
    }
    __syncthreads();

    // ---- layer-2 projections (kg1-verified indexing) ----------------------
    if (n < NN) {
        float accp[4], accr[4];
#pragma unroll
        for (int j = 0; j < 4; ++j) { accp[j] = 0.f; accr[j] = 0.f; }
#pragma unroll
        for (int k2i = 0; k2i < 32; ++k2i) {
            float hk = shh[k2i * 257 + loc];
#pragma unroll
            for (int j = 0; j < 4; ++j) {
                accp[j] += hk * sW2l[k2i * 16 + c * 4 + j];
                accr[j] += hk * sW2r[k2i * 16 + c * 4 + j];
            }
        }
        uint2 up, ur;
        up.x = pack2(accp[0], accp[1]); up.y = pack2(accp[2], accp[3]);
        ur.x = pack2(accr[0], accr[1]); ur.y = pack2(accr[2], accr[3]);
        reinterpret_cast<uint2*>(P2)[(size_t)n * 4 + c] = up;
        reinterpret_cast<uint2*>(R2)[(size_t)n * 4 + c] = ur;
    }
}

// ---- G2: layer2 gather, 4 lanes/node (uint2), fused head (R18-eg2 head) ----
__global__ __launch_bounds__(256) void gather2_kernel(
    const int* __restrict__ rowstart, const int* __restrict__ deg,
    const int* __restrict__ csr_src,
    const __hip_bfloat16* __restrict__ P2,
    const __hip_bfloat16* __restrict__ R2,
    const float* __restrict__ b2,       // [16]
    const float* __restrict__ Wlin,     // [16,2]
    const float* __restrict__ blin,     // [2]
    float* __restrict__ out)            // [NN,2]
{
    __shared__ float sb[16], sW[32], sbl[2];
    if (threadIdx.x < 16) sb[threadIdx.x] = b2[threadIdx.x];
    else if (threadIdx.x < 48) sW[threadIdx.x - 16] = Wlin[threadIdx.x - 16];
    else if (threadIdx.x < 50) sbl[threadIdx.x - 48] = blin[threadIdx.x - 48];
    __syncthreads();
    int t = blockIdx.x * 256 + threadIdx.x;
    int n = t >> 2, c = t & 3;                  // 4 lanes/node: cols c*4..c*4+3
    if (n >= NN) return;
    int start = rowstart[n], dn = deg[n];
    int pv4 = ((dn + 3) & ~3) >> 2;

    const uint2* prow = reinterpret_cast<const uint2*>(P2);  // row = 4 uint2
    const int4* cp4 = reinterpret_cast<const int4*>(csr_src + start);
    uint2 r = reinterpret_cast<const uint2*>(R2)[(size_t)n * 4 + c];
    float acc[4];
#pragma unroll
    for (int j = 0; j < 4; ++j) acc[j] = 0.f;
    int k = 0;
    int4 sA = cp4[0];
    int4 sB = cp4[1];
    for (; k + 1 < pv4; k += 2) {               // 8 neighbor loads in flight
        int4 nA = cp4[k + 2];
        int4 nB = cp4[k + 3];
        uint2 a = prow[(size_t)sA.x * 4 + c];
        uint2 b = prow[(size_t)sA.y * 4 + c];
        uint2 d = prow[(size_t)sA.z * 4 + c];
        uint2 e = prow[(size_t)sA.w * 4 + c];
        uint2 f = prow[(size_t)sB.x * 4 + c];
        uint2 g = prow[(size_t)sB.y * 4 + c];
        uint2 h = prow[(size_t)sB.z * 4 + c];
        uint2 m = prow[(size_t)sB.w * 4 + c];
        acc[0] += bl(a.x) + bl(b.x) + bl(d.x) + bl(e.x)
                + bl(f.x) + bl(g.x) + bl(h.x) + bl(m.x);
        acc[1] += bh(a.x) + bh(b.x) + bh(d.x) + bh(e.x)
                + bh(f.x) + bh(g.x) + bh(h.x) + bh(m.x);
        acc[2] += bl(a.y) + bl(b.y) + bl(d.y) + bl(e.y)
                + bl(f.y) + bl(g.y) + bl(h.y) + bl(m.y);
        acc[3] += bh(a.y) + bh(b.y) + bh(d.y) + bh(e.y)
                + bh(f.y) + bh(g.y) + bh(h.y) + bh(m.y);
        sA = nA; sB = nB;
    }
    if (k < pv4) {                              // odd tail: one quad
        uint2 a = prow[(size_t)sA.x * 4 + c];
        uint2 b = prow[(size_t)sA.y * 4 + c];
        uint2 d = prow[(size_t)sA.z * 4 + c];
        uint2 e = prow[(size_t)sA.w * 4 + c];
        acc[0] += bl(a.x) + bl(b.x) + bl(d.x) + bl(e.x);
        acc[1] += bh(a.x) + bh(b.x) + bh(d.x) + bh(e.x);
        acc[2] += bl(a.y) + bl(b.y) + bl(d.y) + bl(e.y);
        acc[3] += bh(a.y) + bh(b.y) + bh(d.y) + bh(e.y);
    }
    float inv = 1.0f / fmaxf((float)dn, 1.0f);
    float rr[4] = { bl(r.x), bh(r.x), bl(r.y), bh(r.y) };
    float o0 = 0.f, o1 = 0.f;
#pragma unroll
    for (int j = 0; j < 4; ++j) {
        int kk = c * 4 + j;
        float hv = fmaxf(acc[j] * inv + rr[j] + sb[kk], 0.f);
        o0 += hv * sW[kk * 2];
        o1 += hv * sW[kk * 2 + 1];
    }
    o0 += __shfl_xor(o0, 1, 64);                // quad reduce (R18-eg2 head)
    o1 += __shfl_xor(o1, 1, 64);
    o0 += __shfl_xor(o0, 2, 64);
    o1 += __shfl_xor(o1, 2, 64);
    if (c == 0)
        reinterpret_cast<float2*>(out)[n] = make_float2(o0 + sbl[0], o1 + sbl[1]);
}

extern "C" void kernel_launch(void* const* d_in, const int* in_sizes, int n_in,
                              void* d_out, int out_size, void* d_ws, size_t ws_size,
                              hipStream_t stream)
{
    const float* x    = (const float*)d_in[0];
    const int*   ei   = (const int*)d_in[1];
    const float* W1l  = (const float*)d_in[2];
    const float* W1r  = (const float*)d_in[3];
    const float* b1   = (const float*)d_in[4];
    const float* W2l  = (const float*)d_in[5];
    const float* W2r  = (const float*)d_in[6];
    const float* b2   = (const float*)d_in[7];
    const float* Wlin = (const float*)d_in[8];
    const float* blin = (const float*)d_in[9];
    float* out = (float*)d_out;

    // ---- workspace layout (bytes; ws_size = 256 MiB) ----
    char* wsb = (char*)d_ws;
    int*      bsize    = (int*)(wsb + 64);              // int[NB]
    int*      deg      = (int*)(wsb + 4096);            // int[N]
    int*      rowstart = (int*)(wsb + 404096);          // int[N]
    int*      csr_g    = (int*)(wsb + 804096);          // int[NB*SEG] 8.41 MB
    unsigned* bbuf     = (unsigned*)(wsb + 9300000);    // u32[NB*CAP] 7.21 MB
    __hip_bfloat16* p1 = (__hip_bfloat16*)(wsb + 16600000); // bf16[N+1,32]
    __hip_bfloat16* r1 = (__hip_bfloat16*)(wsb + 23100000); // bf16[N,32]
    __hip_bfloat16* p2 = (__hip_bfloat16*)(wsb + 29600000); // bf16[N+1,16]
    __hip_bfloat16* r2 = (__hip_bfloat16*)(wsb + 32900000); // bf16[N+1,16]

    hipMemsetAsync(bsize, 0, NB * sizeof(int), stream);
    k1_kernel<<<2 * NLN + NB1, dim3(256), 0, stream>>>(
        x, W1l, W1r, ei, bsize, bbuf, p1, r1);
    kg1_kernel<<<NB, dim3(1024), 0, stream>>>(
        bsize, bbuf, p1, r1, b1, W2l, W2r, csr_g, deg, rowstart, p2, r2);
    gather2_kernel<<<(NN * 4 + 255) / 256, dim3(256), 0, stream>>>(
        rowstart, deg, csr_g, p2, r2, b2, Wlin, blin, out);
}